// Round 5
// baseline (175.305 us; speedup 1.0000x reference)
//
#include <hip/hip_runtime.h>

// Problem: B=4,S=4096,D=1024,H=16,HID=ATT=64
//   qkv = x @ [Wq|Wk|Wv] + bias       (16384 x 1024) @ (1024 x 3072)
//   per token: scores(16x16) = q k^T / 8 over HID=64; softmax over heads; ctx = P V
// R5: GEMM = R4's counted-vmcnt ring-4 pipeline + R2's PROVEN zero-conflict read
//     geometry (16x16x32 MFMA, 4 quarter-waves per 16-row fragment) + m201's exact
//     two-barrier phase: {reads; stage; MIDbarrier; lgkm0; setprio MFMA} {vmcnt(8);
//     ENDbarrier}. Slot = phase&3, stage 3 slices ahead.

#define AS1 __attribute__((address_space(1)))
#define AS3 __attribute__((address_space(3)))

typedef __bf16 bf16x8 __attribute__((ext_vector_type(8)));
typedef float f32x4 __attribute__((ext_vector_type(4)));
typedef unsigned short u16x8 __attribute__((ext_vector_type(8)));

static constexpr int MTOK = 16384;   // B*S tokens
static constexpr int N3   = 3072;    // 3*H*HID
static constexpr int KD   = 1024;    // D

__device__ __forceinline__ unsigned short f2bf(float f) {
  unsigned u = __float_as_uint(f);
  unsigned r = u + 0x7FFFu + ((u >> 16) & 1u);   // round-to-nearest-even
  return (unsigned short)(r >> 16);
}
__device__ __forceinline__ float bf2f(unsigned short s) {
  return __uint_as_float(((unsigned)s) << 16);
}

__device__ __forceinline__ void gload_lds16(const void* g, void* lds_uniform) {
  __builtin_amdgcn_global_load_lds((const AS1 void*)g, (AS3 void*)lds_uniform, 16, 0, 0);
}

// ---------------- kernel 1: x f32 -> bf16 ----------------
__global__ __launch_bounds__(256) void cvt_x_kernel(const float* __restrict__ x,
                                                    unsigned short* __restrict__ xb) {
  int i = blockIdx.x * 256 + threadIdx.x;      // 8 elements per thread, exact grid
  const float4* p = (const float4*)x;
  float4 a = p[2 * i], b = p[2 * i + 1];
  u16x8 o;
  o[0] = f2bf(a.x); o[1] = f2bf(a.y); o[2] = f2bf(a.z); o[3] = f2bf(a.w);
  o[4] = f2bf(b.x); o[5] = f2bf(b.y); o[6] = f2bf(b.z); o[7] = f2bf(b.w);
  *((u16x8*)xb + i) = o;
}

// ------- kernel 2: W (K x N, f32) -> WT (N x K, bf16), bias concat -------
__global__ __launch_bounds__(256) void prep_w_kernel(const float* __restrict__ Wq,
                                                     const float* __restrict__ Wk,
                                                     const float* __restrict__ Wv,
                                                     const float* __restrict__ bq,
                                                     const float* __restrict__ bk,
                                                     const float* __restrict__ bv,
                                                     unsigned short* __restrict__ WT,
                                                     float* __restrict__ bcat) {
  __shared__ float tile[32][33];
  int kt = blockIdx.x * 32;          // k tile (0..1023)
  int nt = blockIdx.y * 32;          // global n tile (0..3071)
  const float* W; const float* bias; int nb;
  if (nt < 1024)      { W = Wq; bias = bq; nb = nt; }
  else if (nt < 2048) { W = Wk; bias = bk; nb = nt - 1024; }
  else                { W = Wv; bias = bv; nb = nt - 2048; }
  int tx = threadIdx.x & 31, ty = threadIdx.x >> 5;  // ty 0..7
#pragma unroll
  for (int it = 0; it < 4; ++it) {
    int kk = it * 8 + ty;
    tile[kk][tx] = W[(size_t)(kt + kk) * 1024 + nb + tx];
  }
  __syncthreads();
#pragma unroll
  for (int it = 0; it < 4; ++it) {
    int nn = it * 8 + ty;
    WT[(size_t)(nt + nn) * 1024 + kt + tx] = f2bf(tile[tx][nn]);
  }
  if (blockIdx.x == 0 && threadIdx.x < 32)
    bcat[nt + threadIdx.x] = bias[nb + threadIdx.x];
}

// ---------------- kernel 3: GEMM qkv = xb @ WT^T + bias (bf16 out) ----------------
// 256x256 tile, 512 threads = 8 waves (2M x 4N), per-wave C = 128x64 via 8x4 frags
// of v_mfma_f32_16x16x32_bf16. K split into 32 slices of 32.
// LDS: ring of 4 slots (slot = slice&3); slot = A[256][32] (16KB) | B[256][32] (16KB).
//   Layout (R2-proven, 0 conflicts): 16B chunk c of row r at element r*32 + (c ^
//   ((r>>1)&3))*8. gload_lds dest LINEAR (thread t -> t*16B); global SOURCE
//   pre-permuted with the same involution (rule #21).
// Phase p (slice p): reads(12 b128 from slot p&3); STAGE(p+3 -> slot (p+3)&3);
//   MID s_barrier; lgkmcnt(0); setprio(1); 32 MFMA; setprio(0).
// Between phases: vmcnt(8); END s_barrier.  (m201's two-barrier structure.)
// WAR: STAGE(p+3) writes slot (p-1)&3, whose reads were lgkm0-drained before the END
//   barrier of phase p-1, which precedes the stage issue. RAW: vmcnt(8) leaves only
//   stages p+1,p+2 (8 loads) in flight -> slice p landed; barrier makes it global.
//   Tail peels vmcnt 8/8/4/0.
__global__ __launch_bounds__(512, 2) void gemm_qkv_kernel(const unsigned short* __restrict__ A,
                                                          const unsigned short* __restrict__ Bt,
                                                          const float* __restrict__ bias,
                                                          unsigned short* __restrict__ C) {
  __shared__ __align__(16) unsigned short lds[65536];  // 4 slots x 32 KB = 128 KiB
  const int tid  = threadIdx.x;
  const int lane = tid & 63;
  const int wave = tid >> 6;
  const int wm = wave >> 2, wn = wave & 3;   // 2x4 wave grid, per-wave 128x64
  const int m0 = blockIdx.x * 256;
  const int n0 = blockIdx.y * 256;
  const int chunk = lane >> 4;               // logical 16B k-chunk (0..3)
  const int hl = lane & 15;                  // fragment row/col within 16x16

  // staging decode: thread owns linear 16B chunks j=tid, tid+512 of A half (rows
  // j>>2), same for B. chunk j: row=j>>2, phys slot j&3, logical c=(j&3)^((row>>1)&3).
  const int srow = tid >> 2;                               // 0..127
  const int sc   = ((tid & 3) ^ ((srow >> 1) & 3)) * 8;    // logical k-offset (elems)
  const size_t asrc0 = (size_t)(m0 + srow) * KD + sc;
  const size_t asrc1 = (size_t)(m0 + 128 + srow) * KD + sc;  // (r+128): same swizzle bits
  const size_t bsrc0 = (size_t)(n0 + srow) * KD + sc;
  const size_t bsrc1 = (size_t)(n0 + 128 + srow) * KD + sc;

  // fragment ds_read offsets (elements within a slot) — R2 geometry
  int aoff[8], boff[4];
#pragma unroll
  for (int m = 0; m < 8; ++m) {
    int row = wm * 128 + m * 16 + hl;
    aoff[m] = row * 32 + (chunk ^ ((row >> 1) & 3)) * 8;
  }
#pragma unroll
  for (int n = 0; n < 4; ++n) {
    int row = wn * 64 + n * 16 + hl;
    boff[n] = 8192 + row * 32 + (chunk ^ ((row >> 1) & 3)) * 8;
  }

  f32x4 acc[8][4] = {};

#define STAGE(SLOT, KK)                                                        \
  do {                                                                         \
    unsigned short* dst = lds + (SLOT) * 16384 + tid * 8;                      \
    gload_lds16(A  + asrc0 + (KK), dst);                                       \
    gload_lds16(A  + asrc1 + (KK), dst + 4096);                                \
    gload_lds16(Bt + bsrc0 + (KK), dst + 8192);                                \
    gload_lds16(Bt + bsrc1 + (KK), dst + 12288);                               \
  } while (0)

#define PH(SLOT, DOSTAGE, STSLOT, KREAD)                                       \
  do {                                                                         \
    const unsigned short* bufp = lds + (SLOT) * 16384;                         \
    bf16x8 af[8], bfr[4];                                                      \
    _Pragma("unroll") for (int m = 0; m < 8; ++m)                              \
      af[m] = *(const bf16x8*)(bufp + aoff[m]);                                \
    _Pragma("unroll") for (int n = 0; n < 4; ++n)                              \
      bfr[n] = *(const bf16x8*)(bufp + boff[n]);                               \
    if (DOSTAGE) { STAGE(STSLOT, (KREAD) + 96); }                              \
    __builtin_amdgcn_s_barrier();          /* MID barrier */                   \
    asm volatile("s_waitcnt lgkmcnt(0)" ::: "memory");                         \
    __builtin_amdgcn_sched_barrier(0);                                         \
    __builtin_amdgcn_s_setprio(1);                                             \
    _Pragma("unroll") for (int m = 0; m < 8; ++m)                              \
      _Pragma("unroll") for (int n = 0; n < 4; ++n)                            \
        acc[m][n] = __builtin_amdgcn_mfma_f32_16x16x32_bf16(af[m], bfr[n],     \
                                                            acc[m][n], 0, 0, 0);\
    __builtin_amdgcn_s_setprio(0);                                             \
  } while (0)

#define SYNC(VM)                                                               \
  do {                                                                         \
    asm volatile("s_waitcnt vmcnt(" #VM ")" ::: "memory");                     \
    __builtin_amdgcn_s_barrier();          /* END barrier */                   \
    __builtin_amdgcn_sched_barrier(0);                                         \
  } while (0)

  // prologue: stage slices 0,1,2 into slots 0,1,2 (12 loads in flight)
  STAGE(0, 0); STAGE(1, 32); STAGE(2, 64);

  // main: phases p = 4t+i, i=0..3, t=0..6  (p = 0..27); stage slice p+3
#pragma unroll 1
  for (int t = 0; t < 7; ++t) {
    const int kb = t * 128;
    SYNC(8); PH(0, true, 3, kb);
    SYNC(8); PH(1, true, 0, kb + 32);
    SYNC(8); PH(2, true, 1, kb + 64);
    SYNC(8); PH(3, true, 2, kb + 96);
  }
  // tail: p=28 (stage slice 31), then 29,30,31 (nothing left to stage)
  SYNC(8); PH(0, true, 3, 896);
  SYNC(8); PH(1, false, 0, 928);
  SYNC(4); PH(2, false, 0, 960);
  SYNC(0); PH(3, false, 0, 992);
#undef STAGE
#undef PH
#undef SYNC

  // epilogue: 16x16 C/D layout: row = chunk*4 + r, col = hl within each fragment
#pragma unroll
  for (int n = 0; n < 4; ++n) {
    int col = n0 + wn * 64 + n * 16 + hl;
    float bvv = bias[col];
#pragma unroll
    for (int m = 0; m < 8; ++m) {
      int rowb = m0 + wm * 128 + m * 16 + chunk * 4;
#pragma unroll
      for (int r = 0; r < 4; ++r) {
        C[(size_t)(rowb + r) * N3 + col] = f2bf(acc[m][n][r] + bvv);
      }
    }
  }
}

// ---------------- kernel 4: per-token head attention ----------------
// 1 wave per token; scores via 2 MFMAs straight from global; softmax across 16-lane
// groups; P -> LDS; PV on VALU; coalesced f32 out.
__global__ __launch_bounds__(256) void attn_kernel(const unsigned short* __restrict__ qkv,
                                                   float* __restrict__ out) {
  __shared__ float p_lds[4][16][17];
  const int tid = threadIdx.x;
  const int lane = tid & 63;
  const int w = tid >> 6;
  const size_t token = (size_t)blockIdx.x * 4 + w;
  const unsigned short* rowp = qkv + token * N3;
  const int head = lane & 15;     // A-frag row (q head) and B-frag col (k head)
  const int chunk = lane >> 4;    // k-dim subchunk

  const int o = head * 64 + chunk * 8;
  bf16x8 q0 = *(const bf16x8*)(rowp + o);
  bf16x8 q1 = *(const bf16x8*)(rowp + o + 32);
  bf16x8 k0 = *(const bf16x8*)(rowp + 1024 + o);
  bf16x8 k1 = *(const bf16x8*)(rowp + 1024 + o + 32);
  f32x4 c = {0.f, 0.f, 0.f, 0.f};
  c = __builtin_amdgcn_mfma_f32_16x16x32_bf16(q0, k0, c, 0, 0, 0);
  c = __builtin_amdgcn_mfma_f32_16x16x32_bf16(q1, k1, c, 0, 0, 0);
  // c[r] = scores[row = chunk*4+r][col = head]

#pragma unroll
  for (int r = 0; r < 4; ++r) {
    float s = c[r] * 0.125f;
    float m = s;
#pragma unroll
    for (int off = 1; off < 16; off <<= 1) m = fmaxf(m, __shfl_xor(m, off, 64));
    float e = __expf(s - m);
    float sum = e;
#pragma unroll
    for (int off = 1; off < 16; off <<= 1) sum += __shfl_xor(sum, off, 64);
    p_lds[w][chunk * 4 + r][head] = e / sum;
  }
  __syncthreads();

  // PV: lane owns (i = lane>>2, a-block = lane&3): 16 f32 outputs
  const int i = lane >> 2;
  const int ab = lane & 3;
  const unsigned short* vbase = rowp + 2048 + ab * 16;
  float accv[16];
#pragma unroll
  for (int cc = 0; cc < 16; ++cc) accv[cc] = 0.f;
#pragma unroll
  for (int j = 0; j < 16; ++j) {
    float pij = p_lds[w][i][j];
    u16x8 v0 = *(const u16x8*)(vbase + j * 64);
    u16x8 v1 = *(const u16x8*)(vbase + j * 64 + 8);
#pragma unroll
    for (int cc = 0; cc < 8; ++cc) accv[cc] += pij * bf2f(v0[cc]);
#pragma unroll
    for (int cc = 0; cc < 8; ++cc) accv[8 + cc] += pij * bf2f(v1[cc]);
  }
  float* op = out + token * 1024 + i * 64 + ab * 16;
#pragma unroll
  for (int cc = 0; cc < 16; cc += 4) {
    f32x4 v = {accv[cc], accv[cc + 1], accv[cc + 2], accv[cc + 3]};
    *(f32x4*)(op + cc) = v;
  }
}

extern "C" void kernel_launch(void* const* d_in, const int* in_sizes, int n_in,
                              void* d_out, int out_size, void* d_ws, size_t ws_size,
                              hipStream_t stream) {
  const float* x  = (const float*)d_in[0];
  const float* Wq = (const float*)d_in[1];
  const float* bq = (const float*)d_in[2];
  const float* Wk = (const float*)d_in[3];
  const float* bk = (const float*)d_in[4];
  const float* Wv = (const float*)d_in[5];
  const float* bv = (const float*)d_in[6];
  float* out = (float*)d_out;

  char* ws = (char*)d_ws;
  unsigned short* xb   = (unsigned short*)ws;               // 16384*1024*2 = 33,554,432
  unsigned short* WT   = (unsigned short*)(ws + 33554432);  //  3072*1024*2 =  6,291,456
  float*          bcat = (float*)(ws + 39845888);           //  3072*4      =     12,288
  unsigned short* qkv  = (unsigned short*)(ws + 39858176);  // 16384*3072*2 = 100,663,296

  cvt_x_kernel<<<dim3((MTOK * KD / 8) / 256), 256, 0, stream>>>(x, xb);
  prep_w_kernel<<<dim3(32, 96), 256, 0, stream>>>(Wq, Wk, Wv, bq, bk, bv, WT, bcat);
  gemm_qkv_kernel<<<dim3(MTOK / 256, N3 / 256), 512, 0, stream>>>(xb, WT, bcat, qkv);
  attn_kernel<<<dim3(MTOK / 4), 256, 0, stream>>>(qkv, out);
}